// Round 7
// baseline (263.432 us; speedup 1.0000x reference)
//
#include <hip/hip_runtime.h>
#include <hip/hip_bf16.h>
#include <math.h>

// (B,T,E,H) = (4,2048,1024,16), D=64
#define TT 2048
#define HH 16

typedef short s16x8 __attribute__((ext_vector_type(8)));
typedef float f32x4 __attribute__((ext_vector_type(4)));

#define F4(p) (*reinterpret_cast<const float4*>(p))
#define VMCNT(n) asm volatile("s_waitcnt vmcnt(" #n ")" ::: "memory")
#define LGKM0 asm volatile("s_waitcnt lgkmcnt(0)" ::: "memory")
#define SBAR __builtin_amdgcn_s_barrier()
#define SCHEDB __builtin_amdgcn_sched_barrier(0)

__device__ __forceinline__ void gload16(const void* g, void* l) {
    __builtin_amdgcn_global_load_lds(
        (const __attribute__((address_space(1))) void*)g,
        (__attribute__((address_space(3))) void*)l, 16, 0, 0);
}

__device__ __forceinline__ ushort bf1(float a) {
    __hip_bfloat16 h = __float2bfloat16(a);
    union { __hip_bfloat16 h1; ushort u; } c; c.h1 = h; return c.u;
}
__device__ __forceinline__ uint pack_bf2(float a, float b) {
    __hip_bfloat162 h = __float22bfloat162_rn(make_float2(a, b));
    union { __hip_bfloat162 h2; uint u; } c; c.h2 = h; return c.u;
}
__device__ __forceinline__ float fexp2(float x) {
#if __has_builtin(__builtin_amdgcn_exp2f)
    return __builtin_amdgcn_exp2f(x);
#else
    float r; asm("v_exp_f32 %0, %1" : "=v"(r) : "v"(x)); return r;
#endif
}

// ---------------------------------------------------------------------------
// Prep kernel (fused): rope table | x->bf16 | W_attn^T bf16 | W_proj^T bf16
// ---------------------------------------------------------------------------
__global__ __launch_bounds__(256) void prep_kernel(
    const float* __restrict__ x, const float* __restrict__ Wa,
    const float* __restrict__ Wp, ushort* __restrict__ xb,
    ushort* __restrict__ wat, ushort* __restrict__ wpt, float2* __restrict__ cs)
{
    __shared__ float tsh[64][65];
    const int blk = blockIdx.x;
    const int tid = threadIdx.x;

    if (blk < 256) {
        int idx = blk * 256 + tid;
        int t = idx >> 5;
        int i = idx & 31;
        double inv_d = exp(((double)(-2 * i) / 64.0) * log(10000.0));
        float invf = (float)inv_d;
        float freq = (float)t * invf;
        cs[idx] = make_float2((float)cos((double)freq), (float)sin((double)freq));
    } else if (blk < 4352) {
        size_t i = (size_t)(blk - 256) * 2048 + (size_t)tid * 8;
        float4 a = F4(&x[i]); float4 b = F4(&x[i + 4]);
        s16x8 v;
        v[0] = bf1(a.x); v[1] = bf1(a.y); v[2] = bf1(a.z); v[3] = bf1(a.w);
        v[4] = bf1(b.x); v[5] = bf1(b.y); v[6] = bf1(b.z); v[7] = bf1(b.w);
        *reinterpret_cast<s16x8*>(&xb[i]) = v;
    } else {
        const float* in; ushort* out; int R, C, bx, by;
        if (blk < 5120) { int r = blk - 4352; in = Wa; out = wat; R = 1024; C = 3072; bx = r % 48; by = r / 48; }
        else            { int r = blk - 5120; in = Wp; out = wpt; R = 1024; C = 1024; bx = r & 15; by = r >> 4; }
        int r0 = by * 64, c0 = bx * 64;
        int ix = tid & 15, iy = tid >> 4;
#pragma unroll
        for (int j = 0; j < 4; ++j) {
            float4 v = F4(&in[(size_t)(r0 + iy + j * 16) * C + c0 + ix * 4]);
            tsh[iy + j * 16][ix * 4 + 0] = v.x;
            tsh[iy + j * 16][ix * 4 + 1] = v.y;
            tsh[iy + j * 16][ix * 4 + 2] = v.z;
            tsh[iy + j * 16][ix * 4 + 3] = v.w;
        }
        __syncthreads();
        int oc = tid >> 2, seg = tid & 3;
        s16x8 u0, u1;
#pragma unroll
        for (int i = 0; i < 8; ++i) u0[i] = bf1(tsh[seg * 16 + i][oc]);
#pragma unroll
        for (int i = 0; i < 8; ++i) u1[i] = bf1(tsh[seg * 16 + 8 + i][oc]);
        ushort* dst = &out[(size_t)(c0 + oc) * R + r0 + seg * 16];
        *reinterpret_cast<s16x8*>(dst) = u0;
        *reinterpret_cast<s16x8*>(dst + 8) = u1;
    }
}

// ---------------------------------------------------------------------------
// QKV GEMM bf16 MFMA, 4-phase counted-vmcnt pipeline.
// Tile 128x256, BK=64, 256 thr (4 waves 2Mx2N), per-wave 64x128 (4Mf x 8Nf).
// LDS: A dbuf 2x16KB + B single 32KB = 64KB -> 2 blocks/CU. Grid 768 = 3/CU.
// Stages per K-tile (12 gloads): ph1: A0,A2 -> Abuf^1; ph2: B0-3; ph3: B4-7;
// ph4: A1,A3. Waits: vmcnt(2) at loop top, vmcnt(6) before ph3. Never 0.
// Epilogue: bias + RoPE (q scaled by 0.125*log2e) + scatter; v transposed.
// ---------------------------------------------------------------------------
__global__ __launch_bounds__(256, 2) void qkv_gemm_kernel(
    const ushort* __restrict__ xb,    // [8192][1024] bf16
    const ushort* __restrict__ wat,   // [3072][1024] bf16 (W^T)
    const float* __restrict__ bias,   // [3072]
    const float2* __restrict__ cs,    // [2048][32]
    ushort* __restrict__ qg, ushort* __restrict__ kg, ushort* __restrict__ vt)
{
    __shared__ ushort A_s[2][8192];   // [2][128 m][64 k]
    __shared__ ushort B_s[16384];     // [256 n][64 k]

    const int tid = threadIdx.x;
    const int lane = tid & 63, wid = tid >> 6;
    const int lane15 = lane & 15, kgrp = lane >> 4;
    const int wm = wid >> 1, wn = wid & 1;
    const int bid = blockIdx.x;
    const int sbid = (bid & 7) * 96 + (bid >> 3);    // XCD swizzle (768 % 8 == 0)
    const int n0 = (sbid % 12) * 256, m0 = (sbid / 12) * 128;
    const int swz = (lane15 & 7) << 4;
    const int srcsw = ((lane & 7) ^ ((lane >> 3) & 7)) * 8;
    const int kgrp16 = kgrp * 16;
    const float SCL = 0.125f * 1.44269504088896f;

    f32x4 acc[4][8] = {};

    // stage macros: instr covers 32 rows; per wave 8 rows; dst wave-uniform.
#define STG_A(pb, a, kofs)                                                        \
    gload16(xb + (size_t)(m0 + (a) * 32 + wid * 8 + (lane >> 3)) * 1024 + (kofs) + srcsw, \
            &A_s[pb][((a) * 32 + wid * 8) * 64])
#define STG_B(bb, kofs)                                                           \
    gload16(wat + (size_t)(n0 + (bb) * 32 + wid * 8 + (lane >> 3)) * 1024 + (kofs) + srcsw, \
            &B_s[((bb) * 32 + wid * 8) * 64])
#define RD_A(dst, q, ks)                                                          \
    dst = *reinterpret_cast<const s16x8*>(Ap + (wm * 64 + (q) * 16 + lane15) * 128 + (((ks) * 64 + kgrp16) ^ swz))
#define MFMA_Q(q, afr)                                                            \
    do {                                                                          \
        __builtin_amdgcn_s_setprio(1);                                            \
        _Pragma("unroll")                                                         \
        for (int g_ = 0; g_ < 8; ++g_) {                                          \
            acc[q][g_] = __builtin_amdgcn_mfma_f32_16x16x32_bf16(afr[0], bf[g_][0], acc[q][g_], 0, 0, 0); \
            acc[q][g_] = __builtin_amdgcn_mfma_f32_16x16x32_bf16(afr[1], bf[g_][1], acc[q][g_], 0, 0, 0); \
        }                                                                         \
        __builtin_amdgcn_s_setprio(0);                                            \
    } while (0)

    // ---- prologue: stage K-tile 0 fully, drain once ----
#pragma unroll
    for (int a = 0; a < 4; ++a) STG_A(0, a, 0);
#pragma unroll
    for (int b = 0; b < 8; ++b) STG_B(b, 0);
    VMCNT(0);
    SBAR;

    int abuf = 0;
    for (int kt = 0; kt < 16; ++kt) {
        const int kn = (kt < 15 ? kt + 1 : kt) * 64;   // last iter: dummy re-stage
        const int ab2 = abuf ^ 1;
        const char* Ap = (const char*)A_s[abuf];
        const char* Bp = (const char*)B_s;

        // ---- top wait: prev ph1-ph3 stages landed (B all + A0,A2) ----
        VMCNT(2);

        // ---- ph1: read B(16) + A q0; stage A0,A2(next) ----
        s16x8 bf[8][2], af[2];
#pragma unroll
        for (int g = 0; g < 8; ++g) {
            const int rb = (wn * 128 + g * 16 + lane15) * 128;
            bf[g][0] = *reinterpret_cast<const s16x8*>(Bp + rb + (kgrp16 ^ swz));
            bf[g][1] = *reinterpret_cast<const s16x8*>(Bp + rb + ((64 + kgrp16) ^ swz));
        }
        RD_A(af[0], 0, 0); RD_A(af[1], 0, 1);
        STG_A(ab2, 0, kn); STG_A(ab2, 2, kn);
        SBAR; LGKM0; SCHEDB;
        MFMA_Q(0, af);
        SBAR;

        // ---- ph2: read A q1; stage B0-3(next) ----
        RD_A(af[0], 1, 0); RD_A(af[1], 1, 1);
        STG_B(0, kn); STG_B(1, kn); STG_B(2, kn); STG_B(3, kn);
        SBAR; LGKM0; SCHEDB;
        MFMA_Q(1, af);
        SBAR;

        // ---- ph3: wait prev ph4 (A1,A3); read A q2; stage B4-7(next) ----
        VMCNT(6);
        RD_A(af[0], 2, 0); RD_A(af[1], 2, 1);
        STG_B(4, kn); STG_B(5, kn); STG_B(6, kn); STG_B(7, kn);
        SBAR; LGKM0; SCHEDB;
        MFMA_Q(2, af);
        SBAR;

        // ---- ph4: read A q3; stage A1,A3(next) ----
        RD_A(af[0], 3, 0); RD_A(af[1], 3, 1);
        STG_A(ab2, 1, kn); STG_A(ab2, 3, kn);
        SBAR; LGKM0; SCHEDB;
        MFMA_Q(3, af);
        SBAR;

        abuf = ab2;
    }

    // ---- epilogue: bias + rope(q,k) + scatter ----
#pragma unroll
    for (int g = 0; g < 8; ++g) {
        const int n = n0 + wn * 128 + g * 16 + lane15;
        const int sec = n >> 10;
        const int e = n & 1023;
        const int hh = e >> 6, d = e & 63;
        const float bsv = bias[n];
#pragma unroll
        for (int f = 0; f < 4; ++f) {
            const int mb = m0 + wm * 64 + f * 16 + kgrp * 4;
            const int bb = mb >> 11;
            const int t0 = mb & 2047;
            if (sec == 2) {
                float v0 = acc[f][g][0] + bsv, v1 = acc[f][g][1] + bsv;
                float v2 = acc[f][g][2] + bsv, v3 = acc[f][g][3] + bsv;
                uint2 u = make_uint2(pack_bf2(v0, v1), pack_bf2(v2, v3));
                *reinterpret_cast<uint2*>(
                    &vt[((size_t)(bb * HH + hh) * 64 + d) * TT + t0]) = u;
            } else {
                ushort* dst = (sec == 0) ? qg : kg;
#pragma unroll
                for (int r = 0; r < 4; ++r) {
                    float v = acc[f][g][r] + bsv;
                    float p = __shfl_xor(v, 1);
                    float2 c2 = cs[(t0 + r) * 32 + (d >> 1)];
                    float rv = (d & 1) ? (p * c2.y + v * c2.x) : (v * c2.x - p * c2.y);
                    if (sec == 0) rv *= SCL;
                    dst[((size_t)(bb * HH + hh) * TT + t0 + r) * 64 + d] = bf1(rv);
                }
            }
        }
    }
#undef STG_A
#undef STG_B
#undef RD_A
#undef MFMA_Q
}

// ---------------------------------------------------------------------------
// Flash attention bf16 MFMA (unchanged from R6). 512 thr, Q in regs, 48KB LDS,
// defer-max, raw exp2, ones-row l-accumulation.
// ---------------------------------------------------------------------------
__global__ __launch_bounds__(512, 6) void flash_kernel(
    const ushort* __restrict__ qg, const ushort* __restrict__ kg,
    const ushort* __restrict__ vt, ushort* __restrict__ aob)
{
    __shared__ ushort K_s[2][4096];
    __shared__ ushort V_s[2][4096];
    __shared__ ushort P_s[8192];

    const int tid = threadIdx.x;
    const int lane = tid & 63, wid = tid >> 6;
    const int lane15 = lane & 15, kgrp = lane >> 4;
    const int j = blockIdx.x;
    const int qt = 15 - (j >> 6);
    const int bh = j & 63;
    const int b = bh >> 4, h = bh & 15;
    const int q0 = qt * 128;
    const int wq = wid * 16;
    const int wq_abs = q0 + wq;
    const int swz = (lane15 & 7) << 4;
    const int srcsw = ((lane & 7) ^ ((lane >> 3) & 7)) * 8;
    const int kgrp16 = kgrp * 16;
    const int nt = 2 * qt + 2;

    const ushort* qp = qg + (size_t)bh * TT * 64;
    const ushort* kp = kg + (size_t)bh * TT * 64;
    const ushort* vp = vt + (size_t)bh * 64 * TT;
    char* Pw = (char*)P_s + wid * 2048;

#define STAGE_KV(bufi, kv0_)                                                      \
    do {                                                                          \
        gload16(kp + (size_t)((kv0_) + wid * 8 + (lane >> 3)) * 64 + srcsw,       \
                &K_s[bufi][wid * 512]);                                           \
        gload16(vp + (size_t)(wid * 8 + (lane >> 3)) * TT + (kv0_) + srcsw,       \
                &V_s[bufi][wid * 512]);                                           \
    } while (0)

    const ushort* qrow = qp + (size_t)(q0 + wq + lane15) * 64 + kgrp * 8;
    s16x8 qfr[2];
    qfr[0] = *reinterpret_cast<const s16x8*>(qrow);
    qfr[1] = *reinterpret_cast<const s16x8*>(qrow + 32);

    s16x8 ones;
#pragma unroll
    for (int e = 0; e < 8; ++e) ones[e] = (short)0x3F80;

    STAGE_KV(0, 0);

    f32x4 o[5] = {};
    float mreg = -3.0e38f;

    int buf = 0;
    for (int t = 0; t < nt; ++t) {
        __syncthreads();
        if (t + 1 < nt) STAGE_KV(buf ^ 1, (t + 1) * 64);

        const int kv0 = t * 64;
        if (kv0 <= wq_abs + 15) {
            const char* Kp = (const char*)K_s[buf];
            const char* Vp = (const char*)V_s[buf];

            f32x4 sacc[4] = {};
#pragma unroll
            for (int ks = 0; ks < 2; ++ks) {
                const int kb = (ks * 64 + kgrp16) ^ swz;
                s16x8 ka[4];
#pragma unroll
                for (int kf = 0; kf < 4; ++kf)
                    ka[kf] = *reinterpret_cast<const s16x8*>(Kp + (kf * 16 + lane15) * 128 + kb);
                __builtin_amdgcn_s_setprio(1);
#pragma unroll
                for (int kf = 0; kf < 4; ++kf)
                    sacc[kf] = __builtin_amdgcn_mfma_f32_16x16x32_bf16(
                        ka[kf], qfr[ks], sacc[kf], 0, 0, 0);
                __builtin_amdgcn_s_setprio(0);
            }

            const int qglob = q0 + wq + lane15;
            if (kv0 + 63 > wq_abs) {
#pragma unroll
                for (int kf = 0; kf < 4; ++kf)
#pragma unroll
                    for (int r = 0; r < 4; ++r) {
                        int kvg = kv0 + kf * 16 + kgrp * 4 + r;
                        if (kvg > qglob) sacc[kf][r] = -3.0e38f;
                    }
            }
            float t0m = fmaxf(fmaxf(sacc[0][0], sacc[0][1]), sacc[0][2]);
            float t1m = fmaxf(fmaxf(sacc[0][3], sacc[1][0]), sacc[1][1]);
            float t2m = fmaxf(fmaxf(sacc[1][2], sacc[1][3]), sacc[2][0]);
            float t3m = fmaxf(fmaxf(sacc[2][1], sacc[2][2]), sacc[2][3]);
            float t4m = fmaxf(fmaxf(sacc[3][0], sacc[3][1]), sacc[3][2]);
            float mx = fmaxf(fmaxf(fmaxf(t0m, t1m), fmaxf(t2m, t3m)),
                             fmaxf(t4m, sacc[3][3]));
            mx = fmaxf(mx, __shfl_xor(mx, 16));
            mx = fmaxf(mx, __shfl_xor(mx, 32));
            if (!__all(mx <= mreg + 8.f)) {
                const float mnew = fmaxf(mreg, mx);
                const float fs = fexp2(mreg - mnew);
#pragma unroll
                for (int df = 0; df < 5; ++df) o[df] *= fs;
                mreg = mnew;
            }
#pragma unroll
            for (int kf = 0; kf < 4; ++kf) {
                float p0 = fexp2(sacc[kf][0] - mreg);
                float p1 = fexp2(sacc[kf][1] - mreg);
                float p2 = fexp2(sacc[kf][2] - mreg);
                float p3 = fexp2(sacc[kf][3] - mreg);
                uint2 u = make_uint2(pack_bf2(p0, p1), pack_bf2(p2, p3));
                int kvb = (kf * 32 + kgrp * 8) ^ swz;
                *reinterpret_cast<uint2*>(Pw + lane15 * 128 + kvb) = u;
            }

#pragma unroll
            for (int ks = 0; ks < 2; ++ks) {
                const int kb = (ks * 64 + kgrp16) ^ swz;
                s16x8 va[4], pb;
#pragma unroll
                for (int df = 0; df < 4; ++df)
                    va[df] = *reinterpret_cast<const s16x8*>(Vp + (df * 16 + lane15) * 128 + kb);
                pb = *reinterpret_cast<const s16x8*>(Pw + lane15 * 128 + kb);
                __builtin_amdgcn_s_setprio(1);
#pragma unroll
                for (int df = 0; df < 4; ++df)
                    o[df] = __builtin_amdgcn_mfma_f32_16x16x32_bf16(
                        va[df], pb, o[df], 0, 0, 0);
                o[4] = __builtin_amdgcn_mfma_f32_16x16x32_bf16(
                    ones, pb, o[4], 0, 0, 0);
                __builtin_amdgcn_s_setprio(0);
            }
        }
        buf ^= 1;
    }

    {
        const float inv = 1.0f / o[4][0];
        const int row = wq + lane15;
#pragma unroll
        for (int df = 0; df < 4; ++df) {
            float p0 = o[df][0] * inv, p1 = o[df][1] * inv;
            float p2 = o[df][2] * inv, p3 = o[df][3] * inv;
            uint2 u = make_uint2(pack_bf2(p0, p1), pack_bf2(p2, p3));
            int db = (df * 32 + kgrp * 8) ^ ((row & 7) << 4);
            *reinterpret_cast<uint2*>((char*)P_s + row * 128 + db) = u;
        }
    }
    __syncthreads();
    {
        const int q = tid >> 2, seg = tid & 3;
        ushort* orow = aob + ((size_t)(b * TT + q0 + q)) * 1024 + h * 64 + seg * 16;
        int p0 = (seg * 32) ^ ((q & 7) << 4);
        int p1 = (seg * 32 + 16) ^ ((q & 7) << 4);
        s16x8 v0 = *reinterpret_cast<const s16x8*>((const char*)P_s + q * 128 + p0);
        s16x8 v1 = *reinterpret_cast<const s16x8*>((const char*)P_s + q * 128 + p1);
        *reinterpret_cast<s16x8*>(orow) = v0;
        *reinterpret_cast<s16x8*>(orow + 8) = v1;
    }
#undef STAGE_KV
}

// ---------------------------------------------------------------------------
// Proj GEMM bf16 MFMA (unchanged): ao[8192x1024] @ Wp^T + bias -> f32 out
// ---------------------------------------------------------------------------
__global__ __launch_bounds__(256, 2) void proj_gemm_kernel(
    const ushort* __restrict__ ab, const ushort* __restrict__ wpt,
    const float* __restrict__ bias, float* __restrict__ out)
{
    __shared__ ushort As[2][8192];
    __shared__ ushort Bs[2][8192];

    const int tid = threadIdx.x;
    const int lane = tid & 63, wid = tid >> 6;
    const int lane15 = lane & 15, kgrp = lane >> 4;
    const int wr = wid >> 1, wc = wid & 1;
    const int bid = blockIdx.x;
    const int sbid = (bid & 7) * 64 + (bid >> 3);
    const int n0 = (sbid & 7) * 128, m0 = (sbid >> 3) * 128;
    const int swz = (lane15 & 7) << 4;
    const int srcsw = ((lane & 7) ^ ((lane >> 3) & 7)) * 8;
    const int kgrp16 = kgrp * 16;

    f32x4 acc[4][4] = {};

#define STAGE_PRJ(bufi, kofs)                                                     \
    do {                                                                          \
        _Pragma("unroll")                                                         \
        for (int i_ = 0; i_ < 4; ++i_) {                                          \
            int c_ = wid * 4 + i_;                                                \
            gload16(ab + (size_t)(m0 + c_ * 8 + (lane >> 3)) * 1024 + (kofs) + srcsw, \
                    &As[bufi][c_ * 512]);                                         \
            gload16(wpt + (size_t)(n0 + c_ * 8 + (lane >> 3)) * 1024 + (kofs) + srcsw, \
                    &Bs[bufi][c_ * 512]);                                         \
        }                                                                         \
    } while (0)

    STAGE_PRJ(0, 0);
    int buf = 0;
    for (int kt = 0; kt < 16; ++kt) {
        __syncthreads();
        if (kt < 15) STAGE_PRJ(buf ^ 1, (kt + 1) * 64);
        const char* Ap = (const char*)As[buf];
        const char* Bp = (const char*)Bs[buf];
#pragma unroll
        for (int ks = 0; ks < 2; ++ks) {
            s16x8 af[4], bfv[4];
            const int kb = (ks * 64 + kgrp16) ^ swz;
#pragma unroll
            for (int f = 0; f < 4; ++f)
                af[f] = *reinterpret_cast<const s16x8*>(Ap + (wr * 64 + f * 16 + lane15) * 128 + kb);
#pragma unroll
            for (int g = 0; g < 4; ++g)
                bfv[g] = *reinterpret_cast<const s16x8*>(Bp + (wc * 64 + g * 16 + lane15) * 128 + kb);
            __builtin_amdgcn_s_setprio(1);
#pragma unroll
            for (int f = 0; f < 4; ++f)
#pragma unroll
                for (int g = 0; g < 4; ++g)
                    acc[f][g] = __builtin_amdgcn_mfma_f32_16x16x32_bf16(
                        af[f], bfv[g], acc[f][g], 0, 0, 0);
            __builtin_amdgcn_s_setprio(0);
        }
        buf ^= 1;
    }

#pragma unroll
    for (int g = 0; g < 4; ++g) {
        const int n = n0 + wc * 64 + g * 16 + lane15;
        const float bv = bias[n];
#pragma unroll
        for (int f = 0; f < 4; ++f)
#pragma unroll
            for (int r = 0; r < 4; ++r) {
                const int m = m0 + wr * 64 + f * 16 + kgrp * 4 + r;
                out[(size_t)m * 1024 + n] = acc[f][g][r] + bv;
            }
    }
#undef STAGE_PRJ
}

// ---------------------------------------------------------------------------
extern "C" void kernel_launch(void* const* d_in, const int* in_sizes, int n_in,
                              void* d_out, int out_size, void* d_ws, size_t ws_size,
                              hipStream_t stream) {
    const float* x  = (const float*)d_in[0];
    const float* Wa = (const float*)d_in[1];
    const float* ba = (const float*)d_in[2];
    const float* Wp = (const float*)d_in[3];
    const float* bp = (const float*)d_in[4];
    float* out = (float*)d_out;

    char* ws = (char*)d_ws;
    ushort* xb  = (ushort*)(ws + 0);
    ushort* wat = (ushort*)(ws + 16777216);
    ushort* wpt = (ushort*)(ws + 23068672);
    ushort* qg  = (ushort*)(ws + 25165824);
    ushort* kg  = (ushort*)(ws + 41943040);
    ushort* vtg = (ushort*)(ws + 58720256);
    ushort* aob = (ushort*)(ws + 75497472);
    float2* cs  = (float2*)(ws + 92274688);

    prep_kernel<<<dim3(5376), dim3(256), 0, stream>>>(x, Wa, Wp, xb, wat, wpt, cs);
    qkv_gemm_kernel<<<dim3(768), dim3(256), 0, stream>>>(xb, wat, ba, cs, qg, kg, vtg);
    flash_kernel<<<dim3(1024), dim3(512), 0, stream>>>(qg, kg, vtg, aob);
    proj_gemm_kernel<<<dim3(512), dim3(256), 0, stream>>>(aob, wpt, bp, out);
}